// Round 3
// baseline (119.553 us; speedup 1.0000x reference)
//
#include <hip/hip_runtime.h>
#include <math.h>

#define KK 49
#define H 128
#define W 128
#define C 64
#define NB 4
#define EPS 1e-7f
#define PLANE (H * W)

#define TW 16             // tile width (pixels)
#define TH 8              // tile height (pixels)
#define HW2 22            // halo width  = TW + 6
#define HH2 14            // halo height = TH + 6
#define NPOS (HW2 * HH2)  // 308 halo positions
#define NL 25             // window positions per thread (k-split)

// 256 threads: c = tid&15 (pixel col), s = (tid>>4)&1 (k-half), r = tid>>5 (pixel row).
// Each pixel handled by a lane pair (distance 16 within a wave): s=0 owns k 0..24,
// s=1 owns k 24..48 (k=24 is the center — computed by both, s=1 discards it, and it
// doubles as s=1's center read so both halves issue exactly 25+1 ds_read_b128/pass).
// 4 channels staged per pass as float4 (channel-interleaved), double-buffered LDS,
// norms accumulated in registers by each staging-slot owner. Softmax combined across
// the pair via shfl_xor(16). 25 accs/thread -> no VGPR spill (R2's failure mode).
__global__ __launch_bounds__(256, 2) void rsa_kernel(const float* __restrict__ x,
                                                     float* __restrict__ out) {
    __shared__ float4 sx[2][NPOS];  // 9.6 KB
    __shared__ float  snf[NPOS];    // 1.2 KB

    const int tid = threadIdx.x;
    const int c = tid & 15;
    const int s = (tid >> 4) & 1;
    const int r = tid >> 5;
    const int w0 = blockIdx.x * TW;
    const int h0 = blockIdx.y * TH;
    const int b  = blockIdx.z;
    const float* __restrict__ xb = x + (size_t)b * C * PLANE;

    // ---- staging slot metadata (fixed across passes): slot i = tid + 256*j
    int goff[2], pos[2];
    bool act[2], inb[2];
#pragma unroll
    for (int j = 0; j < 2; ++j) {
        int i = tid + j * 256;
        act[j] = (i < NPOS);
        int ii = act[j] ? i : 0;
        int rr = ii / HW2, cc = ii - rr * HW2;
        int gh = h0 - 3 + rr, gw = w0 - 3 + cc;
        inb[j]  = (gh >= 0) && (gh < H) && (gw >= 0) && (gw < W);
        goff[j] = gh * W + gw;
        pos[j]  = ii;
    }

    // ---- per-thread window-address table (25 LDS float4 indices)
    int lofs[NL];
#pragma unroll
    for (int l = 0; l < NL; ++l) {
        int k = l + s * 24;          // s=0: k=0..24 ; s=1: k=24..48
        int di = k / 7, dj = k - di * 7;
        lofs[l] = (r + di) * HW2 + (c + dj);
    }
    const int caddr = (r + 3) * HW2 + (c + 3);

    float4 pf[2];
    float  np[2] = {0.f, 0.f};

    auto load_pass = [&](int t) {
#pragma unroll
        for (int j = 0; j < 2; ++j) {
            float4 v = make_float4(0.f, 0.f, 0.f, 0.f);
            if (act[j] && inb[j]) {
                const float* p = xb + (size_t)(t * 4) * PLANE + goff[j];
                v.x = p[0];
                v.y = p[PLANE];
                v.z = p[2 * PLANE];
                v.w = p[3 * PLANE];
            }
            pf[j] = v;
        }
    };

    auto write_pass = [&](int buf) {
#pragma unroll
        for (int j = 0; j < 2; ++j) {
            if (act[j]) {
                sx[buf][pos[j]] = pf[j];
                float4 v = pf[j];
                np[j] += v.x * v.x + v.y * v.y + v.z * v.z + v.w * v.w;
            }
        }
    };

    float acc[NL];
#pragma unroll
    for (int l = 0; l < NL; ++l) acc[l] = 0.f;

    auto compute = [&](int buf) {
        const float4* __restrict__ base = sx[buf];
        const float4 cv = base[caddr];
#pragma unroll
        for (int l = 0; l < NL; ++l) {
            const float4 nv = base[lofs[l]];
            acc[l] += cv.x * nv.x;
            acc[l] += cv.y * nv.y;
            acc[l] += cv.z * nv.z;
            acc[l] += cv.w * nv.w;
        }
    };

    // ---- software-pipelined main loop: prefetch t+1 while computing t
    load_pass(0);
    write_pass(0);
    __syncthreads();
#pragma unroll 2
    for (int t = 0; t < 16; ++t) {
        const int buf = t & 1;
        if (t < 15) load_pass(t + 1);
        compute(buf);
        if (t < 15) write_pass(buf ^ 1);
        __syncthreads();
    }

    // ---- norms (each slot owner holds the full sum over 64 channels)
#pragma unroll
    for (int j = 0; j < 2; ++j)
        if (act[j]) snf[pos[j]] = sqrtf(np[j]);
    __syncthreads();

    // ---- cosine sim + pairwise softmax over 49
    const float nc = snf[caddr];
    float m = -1e30f;
#pragma unroll
    for (int l = 0; l < NL; ++l) {
        const float nn = snf[lofs[l]];
        const float sv = __fdividef(acc[l], nc * nn + EPS);
        acc[l] = sv;
        if (s == 0 || l > 0) m = fmaxf(m, sv);
    }
    m = fmaxf(m, __shfl_xor(m, 16, 64));

    float sum = 0.f;
#pragma unroll
    for (int l = 0; l < NL; ++l) {
        const float e = __expf(acc[l] - m);
        acc[l] = e;
        if (s == 0 || l > 0) sum += e;
    }
    sum += __shfl_xor(sum, 16, 64);
    const float inv = __fdividef(1.f, sum);

    float* op = out + (((size_t)b * KK) << 14) + ((h0 + r) << 7) + (w0 + c);
#pragma unroll
    for (int l = 0; l < NL; ++l) {
        if (s == 0 || l > 0)
            op[(size_t)(l + s * 24) << 14] = acc[l] * inv;
    }
}

extern "C" void kernel_launch(void* const* d_in, const int* in_sizes, int n_in,
                              void* d_out, int out_size, void* d_ws, size_t ws_size,
                              hipStream_t stream) {
    const float* x = (const float*)d_in[0];
    float* out = (float*)d_out;

    dim3 block(256, 1, 1);
    dim3 grid(W / TW, H / TH, NB);  // 8 x 16 x 4 = 512 blocks (2 per CU)
    rsa_kernel<<<grid, block, 0, stream>>>(x, out);
}